// Round 1
// baseline (295.012 us; speedup 1.0000x reference)
//
#include <hip/hip_runtime.h>

// Problem constants (from reference)
#define BB 16
#define TT 2000
#define FF 481
#define NDF_ 96
#define ORDER_ 5
#define RS (FF * 2)     // 962 floats per (b,t) row
#define TILE 4          // rows per block (TT % TILE == 0 -> block never straddles b)
#define NV (NDF_ / 2)   // 48 float4 slots covering the 192-float filter region
#define CSLOTS 193      // copy slots per row: 192 float4 + 1 float2 (parity peeling)

// spec  : (16, 1, 2000, 481, 2) f32   row stride = 962 floats (3848 B: rows alternate 8/16B align)
// coefs : (16, 2000, 5, 96, 2) f32    per-(b,t) stride = 960 floats (3840 B: always 16B aligned)
// alpha : (16, 2000, 1) f32
// out   : same shape as spec
//
// out[b,t,f<96] = a * (sum_k x[b, t-4+k, f] * c[b,t,k,f]) + (1-a) * x[b,t,f]
//   (complex multiply, zero-padded for t-4+k < 0); tap k==4 IS row t -> reuse for blend.
// out[b,t,f>=96] = spec[b,t,f]

__global__ __launch_bounds__(256) void df_op_kernel(
    const float* __restrict__ spec,
    const float* __restrict__ coefs,
    const float* __restrict__ alpha,
    float* __restrict__ out)
{
    const int tid = threadIdx.x;
    const int bt0 = blockIdx.x * TILE;      // first row of this block
    const int b   = bt0 / TT;
    const int t0  = bt0 - b * TT;

    // ---------------- Phase A: filter, threads 0..191 (3 waves) ----------------
    // thread -> (row r, float4 slot v); v covers complex bins 2v, 2v+1
    if (tid < TILE * NV) {
        const int r  = tid / NV;
        const int v  = tid - r * NV;
        const int t  = t0 + r;
        const int bt = bt0 + r;

        // 5 tap loads (float2 x2 each: spec rows only 8B-aligned on odd bt)
        float2 xs[ORDER_][2];
        #pragma unroll
        for (int k = 0; k < ORDER_; ++k) {
            const int tk = t - (ORDER_ - 1) + k;
            if (tk >= 0) {
                const float* p = spec + (size_t)(b * TT + tk) * RS + v * 4;
                xs[k][0] = *(const float2*)p;
                xs[k][1] = *(const float2*)(p + 2);
            } else {
                xs[k][0] = make_float2(0.0f, 0.0f);
                xs[k][1] = make_float2(0.0f, 0.0f);
            }
        }

        // 5 coef loads, aligned float4 (c.x,c.y = complex coef for bin 2v; c.z,c.w for 2v+1)
        const float4* cp = (const float4*)(coefs + (size_t)bt * (ORDER_ * NDF_ * 2)) + v;
        float4 cs[ORDER_];
        #pragma unroll
        for (int k = 0; k < ORDER_; ++k) cs[k] = cp[(size_t)k * NV];

        float2 a0 = make_float2(0.0f, 0.0f);
        float2 a1 = make_float2(0.0f, 0.0f);
        #pragma unroll
        for (int k = 0; k < ORDER_; ++k) {
            a0.x += xs[k][0].x * cs[k].x - xs[k][0].y * cs[k].y;
            a0.y += xs[k][0].y * cs[k].x + xs[k][0].x * cs[k].y;
            a1.x += xs[k][1].x * cs[k].z - xs[k][1].y * cs[k].w;
            a1.y += xs[k][1].y * cs[k].z + xs[k][1].x * cs[k].w;
        }

        const float a   = alpha[bt];
        const float oma = 1.0f - a;
        // blend input = tap k = ORDER_-1 (tk == t), already in registers
        float2 o0, o1;
        o0.x = a0.x * a + xs[ORDER_ - 1][0].x * oma;
        o0.y = a0.y * a + xs[ORDER_ - 1][0].y * oma;
        o1.x = a1.x * a + xs[ORDER_ - 1][1].x * oma;
        o1.y = a1.y * a + xs[ORDER_ - 1][1].y * oma;

        float* op = out + (size_t)bt * RS + v * 4;
        *(float2*)op       = o0;
        *(float2*)(op + 2) = o1;
    }

    // ---------------- Phase B: copy bins [96,481), all 256 threads ----------------
    // Per row: 770 floats. Even bt (16B-aligned row): 192 float4 @ +192, tail float2 @ +960.
    //          Odd bt  (8B-aligned row):  head float2 @ +192, 192 float4 @ +194.
    #pragma unroll
    for (int i = 0; i < (TILE * CSLOTS + 255) / 256; ++i) {
        const int j = tid + i * 256;
        if (j < TILE * CSLOTS) {
            const int r  = j / CSLOTS;
            const int s  = j - r * CSLOTS;
            const int bt = bt0 + r;
            const size_t rowf = (size_t)bt * RS;
            const int odd = bt & 1;
            if (s < 192) {
                const size_t off = rowf + (NDF_ * 2) + (odd ? 2 : 0) + (size_t)s * 4;
                *(float4*)(out + off) = *(const float4*)(spec + off);
            } else {
                const size_t off = rowf + (odd ? (NDF_ * 2) : (RS - 2));
                *(float2*)(out + off) = *(const float2*)(spec + off);
            }
        }
    }
}

extern "C" void kernel_launch(void* const* d_in, const int* in_sizes, int n_in,
                              void* d_out, int out_size, void* d_ws, size_t ws_size,
                              hipStream_t stream) {
    const float* spec  = (const float*)d_in[0];
    const float* coefs = (const float*)d_in[1];
    const float* alpha = (const float*)d_in[2];
    float* out = (float*)d_out;

    dim3 grid((BB * TT) / TILE);   // 8000 blocks, 4 rows each
    dim3 block(256);
    df_op_kernel<<<grid, block, 0, stream>>>(spec, coefs, alpha, out);
}